// Round 9
// baseline (222.969 us; speedup 1.0000x reference)
//
#include <hip/hip_runtime.h>
#include <math.h>

// Problem constants (from reference setup_inputs)
#define BB 512
#define HH 512
#define RR 2048
#define CC 64
#define OUTD 202          // 3*64 + 2*3 + 4
// params workspace layout per batch (floats)
#define PSTRIDE 208
#define K_OFF 0
#define E_OFF 64
#define A_OFF 128
#define S_OFF 192         // 7 softmaxed shift weights
#define COMBO_OFF 199     // beta / k_n
#define G_OFF 200
#define GAMMA_OFF 201

typedef float f32x4 __attribute__((ext_vector_type(4)));

__device__ __forceinline__ float softplusf_(float x) {
    return (x > 20.f) ? x : log1pf(expf(x));
}
__device__ __forceinline__ float sigmoidf_(float x) {
    return 1.f / (1.f + expf(-x));
}

// ---------------------------------------------------------------------------
// Kernel A: z = h @ fc_w^T + fc_b, activations -> packed params in ws.
// ---------------------------------------------------------------------------
__global__ __launch_bounds__(256) void params_kernel(
    const float* __restrict__ h, const float* __restrict__ fc_w,
    const float* __restrict__ fc_b, float* __restrict__ pw)
{
    __shared__ float h_sh[8][HH];
    __shared__ float z_sh[8][204];
    const int tid = threadIdx.x;
    const int b0 = blockIdx.x * 8;

    for (int idx = tid; idx < 8 * HH; idx += 256) {
        int j = idx >> 9, i = idx & 511;
        h_sh[j][i] = h[(size_t)(b0 + j) * HH + i];
    }
    __syncthreads();

    if (tid < OUTD) {
        float acc[8];
        #pragma unroll
        for (int j = 0; j < 8; ++j) acc[j] = 0.f;
        const float4* wr4 = (const float4*)(fc_w + (size_t)tid * HH);
        for (int i4 = 0; i4 < HH / 4; ++i4) {
            float4 wv = wr4[i4];
            int i = i4 * 4;
            #pragma unroll
            for (int j = 0; j < 8; ++j) {
                acc[j] = fmaf(wv.x, h_sh[j][i + 0], acc[j]);
                acc[j] = fmaf(wv.y, h_sh[j][i + 1], acc[j]);
                acc[j] = fmaf(wv.z, h_sh[j][i + 2], acc[j]);
                acc[j] = fmaf(wv.w, h_sh[j][i + 3], acc[j]);
            }
        }
        float bias = fc_b[tid];
        #pragma unroll
        for (int j = 0; j < 8; ++j) z_sh[j][tid] = acc[j] + bias;
    }
    __syncthreads();

    for (int idx = tid; idx < 8 * OUTD; idx += 256) {
        int j = idx / OUTD;
        int t = idx - j * OUTD;
        float z = z_sh[j][t];
        float* p = pw + (size_t)(b0 + j) * PSTRIDE;
        if (t < 64)            p[K_OFF + t] = tanhf(z);
        else if (t == 65)      p[G_OFF] = sigmoidf_(z);
        else if (t == 73)      p[GAMMA_OFF] = softplusf_(z) + 1.f;
        else if (t >= 74 && t < 138) p[E_OFF + (t - 74)] = sigmoidf_(z);
        else if (t >= 138)     p[A_OFF + (t - 138)] = tanhf(z);
    }
    __syncthreads();

    if (tid < 8) {
        int j = tid;
        float* p = pw + (size_t)(b0 + j) * PSTRIDE;
        float ss = 0.f;
        for (int c = 0; c < 64; ++c) {
            float kv = tanhf(z_sh[j][c]);
            ss += kv * kv;
        }
        float kn = fmaxf(sqrtf(ss), 1e-8f);
        float beta = softplusf_(z_sh[j][64]);
        p[COMBO_OFF] = beta / kn;
        float mx = -1e30f;
        for (int q = 0; q < 7; ++q) mx = fmaxf(mx, z_sh[j][66 + q]);
        float ev[7], se = 0.f;
        for (int q = 0; q < 7; ++q) { ev[q] = expf(z_sh[j][66 + q] - mx); se += ev[q]; }
        float inv = 1.f / se;
        for (int q = 0; q < 7; ++q) p[S_OFF + q] = ev[q] * inv;
    }
}

// ---------------------------------------------------------------------------
// 256-thread block reduce, fixed order -> deterministic
// ---------------------------------------------------------------------------
__device__ __forceinline__ float block_reduce_sum4(float v, float* red) {
    #pragma unroll
    for (int m = 1; m < 64; m <<= 1) v += __shfl_xor(v, m, 64);
    int wid = threadIdx.x >> 6;
    if ((threadIdx.x & 63) == 0) red[wid] = v;
    __syncthreads();
    float x = red[0] + red[1] + red[2] + red[3];
    __syncthreads();
    return x;
}

// ---------------------------------------------------------------------------
// Kernel S: pure read streamer. sc[b][r] = exp(combo*cos_r); per-(b,quarter)
// exp-sum partials -> esum. 2048 blocks x 256 threads (fill-like shape:
// 8 blocks/CU, no barriers except the tiny final reduce). 8 lanes/row
// (32B/lane), 4-row batched loads (8 dwordx4 in flight/thread).
// Max-free softmax is exact: |combo*cos*k_n| <= beta (small).
// ---------------------------------------------------------------------------
__global__ __launch_bounds__(256) void score_kernel(
    const float* __restrict__ memory, const float* __restrict__ pw,
    float* __restrict__ sc, float* __restrict__ esum)
{
    __shared__ float red[4];
    const int tid = threadIdx.x;
    const int b = blockIdx.x >> 2;
    const int rbase = (blockIdx.x & 3) * 512;
    const int lane8 = tid & 7;
    const int rgrp = tid >> 3;            // 0..31
    const float* p = pw + (size_t)b * PSTRIDE;
    const f32x4 ka = *(const f32x4*)(p + K_OFF + lane8 * 8);
    const f32x4 kb = *(const f32x4*)(p + K_OFF + lane8 * 8 + 4);
    const float combo = p[COMBO_OFF];
    const float* memb = memory + (size_t)b * RR * CC;

    float lsum = 0.f;
    #pragma unroll
    for (int mi = 0; mi < 4; ++mi) {
        f32x4 ma[4], mb[4];
        #pragma unroll
        for (int j = 0; j < 4; ++j) {
            int r = rbase + (mi * 4 + j) * 32 + rgrp;
            const f32x4* mp = (const f32x4*)(memb + (size_t)r * CC + lane8 * 8);
            ma[j] = mp[0];
            mb[j] = mp[1];
        }
        #pragma unroll
        for (int j = 0; j < 4; ++j) {
            int r = rbase + (mi * 4 + j) * 32 + rgrp;
            float num = ma[j].x * ka.x + ma[j].y * ka.y + ma[j].z * ka.z
                      + ma[j].w * ka.w + mb[j].x * kb.x + mb[j].y * kb.y
                      + mb[j].z * kb.z + mb[j].w * kb.w;
            float ssq = ma[j].x * ma[j].x + ma[j].y * ma[j].y
                      + ma[j].z * ma[j].z + ma[j].w * ma[j].w
                      + mb[j].x * mb[j].x + mb[j].y * mb[j].y
                      + mb[j].z * mb[j].z + mb[j].w * mb[j].w;
            #pragma unroll
            for (int m = 1; m < 8; m <<= 1) {
                num += __shfl_xor(num, m, 64);
                ssq += __shfl_xor(ssq, m, 64);
            }
            if (lane8 == 0) {
                float mn = fmaxf(sqrtf(ssq), 1e-8f);
                float ev = __expf(combo * num / mn);
                sc[(size_t)b * RR + r] = ev;
                lsum += ev;
            }
        }
    }
    float bs = block_reduce_sum4(lsum, red);
    if (tid == 0) esum[blockIdx.x] = bs;
}

// ---------------------------------------------------------------------------
// Kernel C: quarter-batch gate + 7-tap circular conv + pow -> wp, psum.
// Only a +-3 halo of the gate is recomputed per block (gate is local given
// invse). 2048 blocks x 256 threads, 8 MB total traffic.
// ---------------------------------------------------------------------------
__global__ __launch_bounds__(256) void wconv_kernel(
    const float* __restrict__ sc, const float* __restrict__ prev_w,
    const float* __restrict__ pw, const float* __restrict__ esum,
    float* __restrict__ wp, float* __restrict__ psum)
{
    __shared__ float wgs[518];
    __shared__ float red[4];
    const int tid = threadIdx.x;
    const int b = blockIdx.x >> 2;
    const int r0 = (blockIdx.x & 3) * 512;
    const float* p = pw + (size_t)b * PSTRIDE;
    const float g = p[G_OFF];
    const float gamma = p[GAMMA_OFF];
    const float s0 = p[S_OFF + 0], s1 = p[S_OFF + 1], s2 = p[S_OFF + 2],
                s3 = p[S_OFF + 3], s4 = p[S_OFF + 4], s5 = p[S_OFF + 5],
                s6 = p[S_OFF + 6];
    const float* eb = esum + (size_t)b * 4;
    const float invse = 1.f / (eb[0] + eb[1] + eb[2] + eb[3]);
    const float gi = g * invse, omg = 1.f - g;

    for (int idx = tid; idx < 518; idx += 256) {
        int r = (r0 - 3 + idx) & (RR - 1);
        wgs[idx] = gi * sc[(size_t)b * RR + r]
                 + omg * prev_w[(size_t)b * RR + r];
    }
    __syncthreads();

    float lp = 0.f;
    #pragma unroll
    for (int t2 = 0; t2 < 2; ++t2) {
        int idx = t2 * 256 + tid;
        float acc = s0 * wgs[idx]     + s1 * wgs[idx + 1]
                  + s2 * wgs[idx + 2] + s3 * wgs[idx + 3]
                  + s4 * wgs[idx + 4] + s5 * wgs[idx + 5]
                  + s6 * wgs[idx + 6];
        float v = __powf(acc, gamma);
        wp[(size_t)b * RR + r0 + idx] = v;
        lp += v;
    }
    float bs = block_reduce_sum4(lp, red);
    if (tid == 0) psum[blockIdx.x] = bs;
}

// ---------------------------------------------------------------------------
// Kernel U: pure read+write streamer. Normalizes w on the fly, writes out_w
// and new_mem. 2048 blocks x 256 threads, no barriers, reverse block order
// (read the L3-MRU end of memory first). Plain loads (hit L3 lines score
// allocated) and PLAIN stores (NT stores measured +50% WRITE_SIZE, R7 vs R8).
// 4-row batched loads for ILP.
// ---------------------------------------------------------------------------
__global__ __launch_bounds__(256) void update_kernel(
    const float* __restrict__ memory, const float* __restrict__ wp,
    const float* __restrict__ psum, const float* __restrict__ pw,
    float* __restrict__ out_w, float* __restrict__ out_mem)
{
    const int bid = (int)gridDim.x - 1 - (int)blockIdx.x;
    const int b = bid >> 2;
    const int rbase = (bid & 3) * 512;
    const int tid = threadIdx.x;
    const int lane8 = tid & 7;
    const int rgrp = tid >> 3;            // 0..31
    const float* p = pw + (size_t)b * PSTRIDE;
    const float* pb = psum + (size_t)b * 4;
    const float invp = 1.f / (pb[0] + pb[1] + pb[2] + pb[3] + 1e-16f);
    const f32x4 ea = *(const f32x4*)(p + E_OFF + lane8 * 8);
    const f32x4 eb2 = *(const f32x4*)(p + E_OFF + lane8 * 8 + 4);
    const f32x4 aa = *(const f32x4*)(p + A_OFF + lane8 * 8);
    const f32x4 ab = *(const f32x4*)(p + A_OFF + lane8 * 8 + 4);
    const float* memb = memory + (size_t)b * RR * CC;
    float* omb = out_mem + (size_t)b * RR * CC;

    #pragma unroll
    for (int mi = 0; mi < 4; ++mi) {
        f32x4 ma[4], mb[4];
        float wv[4];
        #pragma unroll
        for (int j = 0; j < 4; ++j) {
            int r = rbase + (mi * 4 + j) * 32 + rgrp;
            const f32x4* mp = (const f32x4*)(memb + (size_t)r * CC + lane8 * 8);
            ma[j] = mp[0];
            mb[j] = mp[1];
            wv[j] = wp[(size_t)b * RR + r] * invp;
        }
        #pragma unroll
        for (int j = 0; j < 4; ++j) {
            int r = rbase + (mi * 4 + j) * 32 + rgrp;
            if (lane8 == 0) out_w[(size_t)b * RR + r] = wv[j];
            f32x4 oa, ob;
            oa.x = ma[j].x * (1.f - wv[j] * ea.x) + wv[j] * aa.x;
            oa.y = ma[j].y * (1.f - wv[j] * ea.y) + wv[j] * aa.y;
            oa.z = ma[j].z * (1.f - wv[j] * ea.z) + wv[j] * aa.z;
            oa.w = ma[j].w * (1.f - wv[j] * ea.w) + wv[j] * aa.w;
            ob.x = mb[j].x * (1.f - wv[j] * eb2.x) + wv[j] * ab.x;
            ob.y = mb[j].y * (1.f - wv[j] * eb2.y) + wv[j] * ab.y;
            ob.z = mb[j].z * (1.f - wv[j] * eb2.z) + wv[j] * ab.z;
            ob.w = mb[j].w * (1.f - wv[j] * eb2.w) + wv[j] * ab.w;
            f32x4* op = (f32x4*)(omb + (size_t)r * CC + lane8 * 8);
            op[0] = oa;
            op[1] = ob;
        }
    }
}

// ---------------------------------------------------------------------------
// Fallback (ws too small): R8 fused kernel (correct, 182 us).
// ---------------------------------------------------------------------------
__device__ __forceinline__ float block_reduce_sum16(float v, float* red) {
    #pragma unroll
    for (int m = 1; m < 64; m <<= 1) v += __shfl_xor(v, m, 64);
    int wid = threadIdx.x >> 6;
    if ((threadIdx.x & 63) == 0) red[wid] = v;
    __syncthreads();
    if (threadIdx.x < 16) {
        float x = red[threadIdx.x];
        #pragma unroll
        for (int m = 1; m < 16; m <<= 1) x += __shfl_xor(x, m, 64);
        if (threadIdx.x == 0) red[0] = x;
    }
    __syncthreads();
    float r = red[0];
    __syncthreads();
    return r;
}

__global__ __launch_bounds__(1024) void fused_kernel_fb(
    const float* __restrict__ memory, const float* __restrict__ prev_w,
    const float* __restrict__ pw, float* __restrict__ out_w,
    float* __restrict__ out_mem)
{
    __shared__ float evs[RR];
    __shared__ float wg[RR];
    __shared__ float red[16];
    const int b = blockIdx.x;
    const int tid = threadIdx.x;
    const int lane8 = tid & 7;
    const int rgrp = tid >> 3;
    const float* p = pw + (size_t)b * PSTRIDE;
    const f32x4 ka = *(const f32x4*)(p + K_OFF + lane8 * 8);
    const f32x4 kb = *(const f32x4*)(p + K_OFF + lane8 * 8 + 4);
    const float combo = p[COMBO_OFF];
    const float* memb = memory + (size_t)b * RR * CC;

    float lsum = 0.f;
    #pragma unroll 8
    for (int i = 0; i < 16; ++i) {
        int r = i * 128 + rgrp;
        const f32x4* mp = (const f32x4*)(memb + (size_t)r * CC + lane8 * 8);
        f32x4 ma = mp[0], mb = mp[1];
        float num = ma.x * ka.x + ma.y * ka.y + ma.z * ka.z + ma.w * ka.w
                  + mb.x * kb.x + mb.y * kb.y + mb.z * kb.z + mb.w * kb.w;
        float ssq = ma.x * ma.x + ma.y * ma.y + ma.z * ma.z + ma.w * ma.w
                  + mb.x * mb.x + mb.y * mb.y + mb.z * mb.z + mb.w * mb.w;
        #pragma unroll
        for (int m = 1; m < 8; m <<= 1) {
            num += __shfl_xor(num, m, 64);
            ssq += __shfl_xor(ssq, m, 64);
        }
        if (lane8 == 0) {
            float ev = __expf(combo * num / fmaxf(sqrtf(ssq), 1e-8f));
            evs[r] = ev;
            lsum += ev;
        }
    }
    const float se = block_reduce_sum16(lsum, red);
    const float g = p[G_OFF], gamma = p[GAMMA_OFF];
    const float s0 = p[S_OFF + 0], s1 = p[S_OFF + 1], s2 = p[S_OFF + 2],
                s3 = p[S_OFF + 3], s4 = p[S_OFF + 4], s5 = p[S_OFF + 5],
                s6 = p[S_OFF + 6];
    const float gi = g / se, omg = 1.f - g;
    {
        const int r2 = tid * 2;
        float2 pv = *(const float2*)(prev_w + (size_t)b * RR + r2);
        wg[r2]     = gi * evs[r2]     + omg * pv.x;
        wg[r2 + 1] = gi * evs[r2 + 1] + omg * pv.y;
    }
    __syncthreads();
    float lp = 0.f;
    {
        const int r2 = tid * 2;
        #pragma unroll
        for (int q = 0; q < 2; ++q) {
            int r = r2 + q;
            float acc = s0 * wg[(r - 3) & (RR - 1)] + s1 * wg[(r - 2) & (RR - 1)]
                      + s2 * wg[(r - 1) & (RR - 1)] + s3 * wg[r]
                      + s4 * wg[(r + 1) & (RR - 1)] + s5 * wg[(r + 2) & (RR - 1)]
                      + s6 * wg[(r + 3) & (RR - 1)];
            float v = __powf(acc, gamma);
            evs[r] = v;
            lp += v;
        }
    }
    const float ps = block_reduce_sum16(lp, red);
    const float invp = 1.f / (ps + 1e-16f);
    {
        const int r2 = tid * 2;
        float w0 = evs[r2] * invp, w1 = evs[r2 + 1] * invp;
        wg[r2] = w0;
        wg[r2 + 1] = w1;
        *(float2*)(out_w + (size_t)b * RR + r2) = make_float2(w0, w1);
    }
    __syncthreads();
    const f32x4 ea = *(const f32x4*)(p + E_OFF + lane8 * 8);
    const f32x4 eb2 = *(const f32x4*)(p + E_OFF + lane8 * 8 + 4);
    const f32x4 aa = *(const f32x4*)(p + A_OFF + lane8 * 8);
    const f32x4 ab = *(const f32x4*)(p + A_OFF + lane8 * 8 + 4);
    float* omb = out_mem + (size_t)b * RR * CC;
    #pragma unroll 8
    for (int i = 0; i < 16; ++i) {
        int r = i * 128 + rgrp;
        float wv = wg[r];
        const f32x4* mp = (const f32x4*)(memb + (size_t)r * CC + lane8 * 8);
        f32x4 ma = mp[0], mb = mp[1];
        f32x4 oa, ob;
        oa.x = ma.x * (1.f - wv * ea.x) + wv * aa.x;
        oa.y = ma.y * (1.f - wv * ea.y) + wv * aa.y;
        oa.z = ma.z * (1.f - wv * ea.z) + wv * aa.z;
        oa.w = ma.w * (1.f - wv * ea.w) + wv * aa.w;
        ob.x = mb.x * (1.f - wv * eb2.x) + wv * ab.x;
        ob.y = mb.y * (1.f - wv * eb2.y) + wv * ab.y;
        ob.z = mb.z * (1.f - wv * eb2.z) + wv * ab.z;
        ob.w = mb.w * (1.f - wv * eb2.w) + wv * ab.w;
        f32x4* op = (f32x4*)(omb + (size_t)r * CC + lane8 * 8);
        op[0] = oa;
        op[1] = ob;
    }
}

extern "C" void kernel_launch(void* const* d_in, const int* in_sizes, int n_in,
                              void* d_out, int out_size, void* d_ws, size_t ws_size,
                              hipStream_t stream) {
    const float* h      = (const float*)d_in[0];
    const float* prev_w = (const float*)d_in[1];
    const float* memory = (const float*)d_in[2];
    const float* fc_w   = (const float*)d_in[3];
    const float* fc_b   = (const float*)d_in[4];

    float* pw      = (float*)d_ws;              // 512*208 floats
    float* out_w   = (float*)d_out;             // B*R
    float* out_mem = out_w + (size_t)BB * RR;   // B*R*C

    const size_t pw_f   = (size_t)BB * PSTRIDE;
    const size_t br_f   = (size_t)BB * RR;
    const size_t need_f = pw_f + 2 * br_f + 2 * (size_t)BB * 4;

    params_kernel<<<64, 256, 0, stream>>>(h, fc_w, fc_b, pw);

    if (ws_size >= need_f * sizeof(float)) {
        float* sc   = pw + pw_f;
        float* wpb  = sc + br_f;
        float* esum = wpb + br_f;
        float* psum = esum + (size_t)BB * 4;
        score_kernel<<<BB * 4, 256, 0, stream>>>(memory, pw, sc, esum);
        wconv_kernel<<<BB * 4, 256, 0, stream>>>(sc, prev_w, pw, esum, wpb, psum);
        update_kernel<<<BB * 4, 256, 0, stream>>>(memory, wpb, psum, pw,
                                                  out_w, out_mem);
    } else {
        fused_kernel_fb<<<BB, 1024, 0, stream>>>(memory, prev_w, pw,
                                                 out_w, out_mem);
    }
}

// Round 10
// 204.878 us; speedup vs baseline: 1.0883x; 1.0883x over previous
//
#include <hip/hip_runtime.h>
#include <math.h>

// Problem constants (from reference setup_inputs)
#define BB 512
#define HH 512
#define RR 2048
#define CC 64
#define OUTD 202          // 3*64 + 2*3 + 4
// params workspace layout per batch (floats)
#define PSTRIDE 208
#define K_OFF 0
#define E_OFF 64
#define A_OFF 128
#define S_OFF 192         // 7 softmaxed shift weights
#define COMBO_OFF 199     // beta / k_n
#define G_OFF 200
#define GAMMA_OFF 201

typedef float f32x4 __attribute__((ext_vector_type(4)));

__device__ __forceinline__ float softplusf_(float x) {
    return (x > 20.f) ? x : log1pf(expf(x));
}
__device__ __forceinline__ float sigmoidf_(float x) {
    return 1.f / (1.f + expf(-x));
}

// ---------------------------------------------------------------------------
// Kernel A v2: one block per batch (512 x 256). Each thread t<202 computes
// z[b][t] = h[b] . fc_w[t] + fc_b[t] (h staged in LDS; fc_w is 414 KB ->
// L2-resident per XCD after first touch). Wave 0 then finishes the per-batch
// scalars (combo = beta/||k||, 7-tap shift softmax). Replaces the 64-block
// version measured at ~35 us (25% CU util, latency-bound).
// ---------------------------------------------------------------------------
__global__ __launch_bounds__(256) void params_kernel(
    const float* __restrict__ h, const float* __restrict__ fc_w,
    const float* __restrict__ fc_b, float* __restrict__ pw)
{
    __shared__ float h_sh[HH];
    __shared__ float z_sh[80];         // raw z for t < 74
    const int b = blockIdx.x;
    const int tid = threadIdx.x;
    float* p = pw + (size_t)b * PSTRIDE;

    *(float2*)(h_sh + tid * 2) = *(const float2*)(h + (size_t)b * HH + tid * 2);
    __syncthreads();

    if (tid < OUTD) {
        const float4* wr = (const float4*)(fc_w + (size_t)tid * HH);
        float acc = 0.f;
        #pragma unroll 4
        for (int i = 0; i < HH / 4; ++i) {
            float4 wv = wr[i];
            acc += wv.x * h_sh[4 * i]     + wv.y * h_sh[4 * i + 1]
                 + wv.z * h_sh[4 * i + 2] + wv.w * h_sh[4 * i + 3];
        }
        float z = acc + fc_b[tid];
        if (tid < 74) z_sh[tid] = z;
        if (tid < 64)                      p[K_OFF + tid] = tanhf(z);
        else if (tid == 65)                p[G_OFF] = sigmoidf_(z);
        else if (tid == 73)                p[GAMMA_OFF] = softplusf_(z) + 1.f;
        else if (tid >= 74 && tid < 138)   p[E_OFF + (tid - 74)] = sigmoidf_(z);
        else if (tid >= 138)               p[A_OFF + (tid - 138)] = tanhf(z);
    }
    __syncthreads();

    if (tid < 64) {
        float kv = tanhf(z_sh[tid]);
        float ss = kv * kv;
        #pragma unroll
        for (int m = 1; m < 64; m <<= 1) ss += __shfl_xor(ss, m, 64);
        if (tid == 0) {
            float kn = fmaxf(sqrtf(ss), 1e-8f);
            float beta = softplusf_(z_sh[64]);
            p[COMBO_OFF] = beta / kn;
            float mx = -1e30f;
            #pragma unroll
            for (int q = 0; q < 7; ++q) mx = fmaxf(mx, z_sh[66 + q]);
            float ev[7], se = 0.f;
            #pragma unroll
            for (int q = 0; q < 7; ++q) {
                ev[q] = __expf(z_sh[66 + q] - mx);
                se += ev[q];
            }
            float inv = 1.f / se;
            #pragma unroll
            for (int q = 0; q < 7; ++q) p[S_OFF + q] = ev[q] * inv;
        }
    }
}

// ---------------------------------------------------------------------------
// 256-thread block reduce, fixed order -> deterministic
// ---------------------------------------------------------------------------
__device__ __forceinline__ float block_reduce_sum4(float v, float* red) {
    #pragma unroll
    for (int m = 1; m < 64; m <<= 1) v += __shfl_xor(v, m, 64);
    int wid = threadIdx.x >> 6;
    if ((threadIdx.x & 63) == 0) red[wid] = v;
    __syncthreads();
    float x = red[0] + red[1] + red[2] + red[3];
    __syncthreads();
    return x;
}

// ---------------------------------------------------------------------------
// Kernel S: pure read streamer (fill-like: 2048 x 256, 8 blocks/CU).
// sc[b][r] = exp(combo*cos_r); per-(b,quarter) exp-sums -> esum.
// 8 lanes/row (32B/lane), 4-row batched loads. Max-free softmax is exact.
// ---------------------------------------------------------------------------
__global__ __launch_bounds__(256) void score_kernel(
    const float* __restrict__ memory, const float* __restrict__ pw,
    float* __restrict__ sc, float* __restrict__ esum)
{
    __shared__ float red[4];
    const int tid = threadIdx.x;
    const int b = blockIdx.x >> 2;
    const int rbase = (blockIdx.x & 3) * 512;
    const int lane8 = tid & 7;
    const int rgrp = tid >> 3;            // 0..31
    const float* p = pw + (size_t)b * PSTRIDE;
    const f32x4 ka = *(const f32x4*)(p + K_OFF + lane8 * 8);
    const f32x4 kb = *(const f32x4*)(p + K_OFF + lane8 * 8 + 4);
    const float combo = p[COMBO_OFF];
    const float* memb = memory + (size_t)b * RR * CC;

    float lsum = 0.f;
    #pragma unroll
    for (int mi = 0; mi < 4; ++mi) {
        f32x4 ma[4], mb[4];
        #pragma unroll
        for (int j = 0; j < 4; ++j) {
            int r = rbase + (mi * 4 + j) * 32 + rgrp;
            const f32x4* mp = (const f32x4*)(memb + (size_t)r * CC + lane8 * 8);
            ma[j] = mp[0];
            mb[j] = mp[1];
        }
        #pragma unroll
        for (int j = 0; j < 4; ++j) {
            int r = rbase + (mi * 4 + j) * 32 + rgrp;
            float num = ma[j].x * ka.x + ma[j].y * ka.y + ma[j].z * ka.z
                      + ma[j].w * ka.w + mb[j].x * kb.x + mb[j].y * kb.y
                      + mb[j].z * kb.z + mb[j].w * kb.w;
            float ssq = ma[j].x * ma[j].x + ma[j].y * ma[j].y
                      + ma[j].z * ma[j].z + ma[j].w * ma[j].w
                      + mb[j].x * mb[j].x + mb[j].y * mb[j].y
                      + mb[j].z * mb[j].z + mb[j].w * mb[j].w;
            #pragma unroll
            for (int m = 1; m < 8; m <<= 1) {
                num += __shfl_xor(num, m, 64);
                ssq += __shfl_xor(ssq, m, 64);
            }
            if (lane8 == 0) {
                float mn = fmaxf(sqrtf(ssq), 1e-8f);
                float ev = __expf(combo * num / mn);
                sc[(size_t)b * RR + r] = ev;
                lsum += ev;
            }
        }
    }
    float bs = block_reduce_sum4(lsum, red);
    if (tid == 0) esum[blockIdx.x] = bs;
}

// ---------------------------------------------------------------------------
// 16-wave (1024-thread) block reduce, fixed order -> deterministic
// ---------------------------------------------------------------------------
__device__ __forceinline__ float block_reduce_sum16(float v, float* red) {
    #pragma unroll
    for (int m = 1; m < 64; m <<= 1) v += __shfl_xor(v, m, 64);
    int wid = threadIdx.x >> 6;
    if ((threadIdx.x & 63) == 0) red[wid] = v;
    __syncthreads();
    if (threadIdx.x < 16) {
        float x = red[threadIdx.x];
        #pragma unroll
        for (int m = 1; m < 16; m <<= 1) x += __shfl_xor(x, m, 64);
        if (threadIdx.x == 0) red[0] = x;
    }
    __syncthreads();
    float r = red[0];
    __syncthreads();
    return r;
}

// ---------------------------------------------------------------------------
// Kernel WU: per-batch weight pipeline + memory update (R4 structure with
// R8 lessons: plain loads, PLAIN stores, 4-row batched phase-B loads).
// 512 blocks x 1024 threads. w stays in LDS between phases.
// ---------------------------------------------------------------------------
__global__ __launch_bounds__(1024) void wu_kernel(
    const float* __restrict__ memory, const float* __restrict__ sc,
    const float* __restrict__ esum, const float* __restrict__ prev_w,
    const float* __restrict__ pw, float* __restrict__ out_w,
    float* __restrict__ out_mem)
{
    __shared__ float wg[RR];       // gated weights -> final w
    __shared__ float wps[RR];      // w_p
    __shared__ float red[16];

    const int b = blockIdx.x;
    const int tid = threadIdx.x;
    const float* p = pw + (size_t)b * PSTRIDE;
    const float g = p[G_OFF];
    const float gamma = p[GAMMA_OFF];
    const float s0 = p[S_OFF + 0], s1 = p[S_OFF + 1], s2 = p[S_OFF + 2],
                s3 = p[S_OFF + 3], s4 = p[S_OFF + 4], s5 = p[S_OFF + 5],
                s6 = p[S_OFF + 6];
    const float* eb = esum + (size_t)b * 4;
    const float se = eb[0] + eb[1] + eb[2] + eb[3];
    const float gi = g / se, omg = 1.f - g;

    // gate: 2 rows/thread, float2 loads of sc and prev_w
    {
        const int r2 = tid * 2;
        float2 ev = *(const float2*)(sc + (size_t)b * RR + r2);
        float2 pv = *(const float2*)(prev_w + (size_t)b * RR + r2);
        wg[r2]     = gi * ev.x + omg * pv.x;
        wg[r2 + 1] = gi * ev.y + omg * pv.y;
    }
    __syncthreads();

    // 7-tap circular conv + pow
    float lp = 0.f;
    {
        const int r2 = tid * 2;
        #pragma unroll
        for (int q = 0; q < 2; ++q) {
            int r = r2 + q;
            float acc = s0 * wg[(r - 3) & (RR - 1)]
                      + s1 * wg[(r - 2) & (RR - 1)]
                      + s2 * wg[(r - 1) & (RR - 1)]
                      + s3 * wg[r]
                      + s4 * wg[(r + 1) & (RR - 1)]
                      + s5 * wg[(r + 2) & (RR - 1)]
                      + s6 * wg[(r + 3) & (RR - 1)];
            float v = __powf(acc, gamma);
            wps[r] = v;
            lp += v;
        }
    }
    const float ps = block_reduce_sum16(lp, red);   // internal barrier: conv done
    const float invp = 1.f / (ps + 1e-16f);

    // normalize -> out_w + stash w in wg for phase B
    {
        const int r2 = tid * 2;
        float w0 = wps[r2] * invp;
        float w1 = wps[r2 + 1] * invp;
        wg[r2] = w0;
        wg[r2 + 1] = w1;
        *(float2*)(out_w + (size_t)b * RR + r2) = make_float2(w0, w1);
    }
    __syncthreads();

    // phase B: memory update. 8 lanes/row, 4-row batched loads, plain stores.
    const int lane8 = tid & 7;
    const int rgrp = tid >> 3;             // 0..127
    const f32x4 ea = *(const f32x4*)(p + E_OFF + lane8 * 8);
    const f32x4 eb2 = *(const f32x4*)(p + E_OFF + lane8 * 8 + 4);
    const f32x4 aa = *(const f32x4*)(p + A_OFF + lane8 * 8);
    const f32x4 ab = *(const f32x4*)(p + A_OFF + lane8 * 8 + 4);
    const float* memb = memory + (size_t)b * RR * CC;
    float* omb = out_mem + (size_t)b * RR * CC;

    #pragma unroll
    for (int mi = 0; mi < 4; ++mi) {
        f32x4 ma[4], mb[4];
        float wv[4];
        #pragma unroll
        for (int j = 0; j < 4; ++j) {
            int r = (mi * 4 + j) * 128 + rgrp;
            const f32x4* mp = (const f32x4*)(memb + (size_t)r * CC + lane8 * 8);
            ma[j] = mp[0];
            mb[j] = mp[1];
            wv[j] = wg[r];
        }
        #pragma unroll
        for (int j = 0; j < 4; ++j) {
            int r = (mi * 4 + j) * 128 + rgrp;
            f32x4 oa, ob;
            oa.x = ma[j].x * (1.f - wv[j] * ea.x) + wv[j] * aa.x;
            oa.y = ma[j].y * (1.f - wv[j] * ea.y) + wv[j] * aa.y;
            oa.z = ma[j].z * (1.f - wv[j] * ea.z) + wv[j] * aa.z;
            oa.w = ma[j].w * (1.f - wv[j] * ea.w) + wv[j] * aa.w;
            ob.x = mb[j].x * (1.f - wv[j] * eb2.x) + wv[j] * ab.x;
            ob.y = mb[j].y * (1.f - wv[j] * eb2.y) + wv[j] * ab.y;
            ob.z = mb[j].z * (1.f - wv[j] * eb2.z) + wv[j] * ab.z;
            ob.w = mb[j].w * (1.f - wv[j] * eb2.w) + wv[j] * ab.w;
            f32x4* op = (f32x4*)(omb + (size_t)r * CC + lane8 * 8);
            op[0] = oa;
            op[1] = ob;
        }
    }
}

extern "C" void kernel_launch(void* const* d_in, const int* in_sizes, int n_in,
                              void* d_out, int out_size, void* d_ws, size_t ws_size,
                              hipStream_t stream) {
    const float* h      = (const float*)d_in[0];
    const float* prev_w = (const float*)d_in[1];
    const float* memory = (const float*)d_in[2];
    const float* fc_w   = (const float*)d_in[3];
    const float* fc_b   = (const float*)d_in[4];

    float* pw      = (float*)d_ws;              // 512*208 floats
    float* out_w   = (float*)d_out;             // B*R
    float* out_mem = out_w + (size_t)BB * RR;   // B*R*C

    const size_t pw_f   = (size_t)BB * PSTRIDE;
    const size_t br_f   = (size_t)BB * RR;
    const size_t need_f = pw_f + br_f + (size_t)BB * 4;

    params_kernel<<<BB, 256, 0, stream>>>(h, fc_w, fc_b, pw);

    if (ws_size >= need_f * sizeof(float)) {
        float* sc   = pw + pw_f;
        float* esum = sc + br_f;
        score_kernel<<<BB * 4, 256, 0, stream>>>(memory, pw, sc, esum);
        wu_kernel<<<BB, 1024, 0, stream>>>(memory, sc, esum, prev_w, pw,
                                           out_w, out_mem);
    } else {
        // minimal fallback (should not trigger: need ~4.6 MB, ws is ~800 MB):
        // score into out_mem head, then WU reading it (ordered by dispatch).
        float* sc   = out_mem;
        float* esum = pw + pw_f;
        score_kernel<<<BB * 4, 256, 0, stream>>>(memory, pw, sc, esum);
        wu_kernel<<<BB, 1024, 0, stream>>>(memory, sc, esum, prev_w, pw,
                                           out_w, out_mem);
    }
}

// Round 11
// 191.397 us; speedup vs baseline: 1.1650x; 1.0704x over previous
//
#include <hip/hip_runtime.h>
#include <math.h>

// Problem constants (from reference setup_inputs)
#define BB 512
#define HH 512
#define RR 2048
#define CC 64
#define OUTD 202          // 3*64 + 2*3 + 4
// params workspace layout per batch (floats)
#define PSTRIDE 208
#define K_OFF 0
#define E_OFF 64
#define A_OFF 128
#define S_OFF 192         // 7 softmaxed shift weights
#define COMBO_OFF 199     // beta / k_n
#define G_OFF 200
#define GAMMA_OFF 201

#define PART_STRIDE 224   // padded 202, per (batch, hq) partial row

typedef float f32x4 __attribute__((ext_vector_type(4)));

__device__ __forceinline__ float softplusf_(float x) {
    return (x > 20.f) ? x : log1pf(expf(x));
}
__device__ __forceinline__ float sigmoidf_(float x) {
    return 1.f / (1.f + expf(-x));
}

// ---------------------------------------------------------------------------
// Kernel A1: split-K partial GEMM. grid 256 = 64 batch-groups x 4 H-quarters.
// Each block stages h[8 batches][128] in LDS; thread t<202 accumulates
// acc[8] over its fc_w row chunk (8-batch reuse keeps total L2 requests at
// the v1 level while running on 4x the blocks).
// part[b][hq][t] = partial dot.
// ---------------------------------------------------------------------------
__global__ __launch_bounds__(256) void params_part_kernel(
    const float* __restrict__ h, const float* __restrict__ fc_w,
    float* __restrict__ part)
{
    __shared__ float h_sh[8][128];
    const int tid = threadIdx.x;
    const int bg = blockIdx.x >> 2;
    const int hq = blockIdx.x & 3;
    const int b0 = bg * 8;
    const int h0 = hq * 128;

    for (int idx = tid; idx < 8 * 128; idx += 256) {
        int j = idx >> 7, i = idx & 127;
        h_sh[j][i] = h[(size_t)(b0 + j) * HH + h0 + i];
    }
    __syncthreads();

    if (tid < OUTD) {
        float acc[8];
        #pragma unroll
        for (int j = 0; j < 8; ++j) acc[j] = 0.f;
        const float4* wr = (const float4*)(fc_w + (size_t)tid * HH + h0);
        #pragma unroll 4
        for (int i4 = 0; i4 < 32; ++i4) {
            float4 wv = wr[i4];
            int i = i4 * 4;
            #pragma unroll
            for (int j = 0; j < 8; ++j) {
                acc[j] = fmaf(wv.x, h_sh[j][i + 0], acc[j]);
                acc[j] = fmaf(wv.y, h_sh[j][i + 1], acc[j]);
                acc[j] = fmaf(wv.z, h_sh[j][i + 2], acc[j]);
                acc[j] = fmaf(wv.w, h_sh[j][i + 3], acc[j]);
            }
        }
        #pragma unroll
        for (int j = 0; j < 8; ++j) {
            part[((size_t)(b0 + j) * 4 + hq) * PART_STRIDE + tid] = acc[j];
        }
    }
}

// ---------------------------------------------------------------------------
// Kernel A2: combine partials + bias -> activations -> packed params.
// 512 blocks x 256 threads (one per batch). Wave 0 finishes per-batch
// scalars (combo = beta/||k||, 7-tap shift softmax).
// ---------------------------------------------------------------------------
__global__ __launch_bounds__(256) void params_combine_kernel(
    const float* __restrict__ part, const float* __restrict__ fc_b,
    float* __restrict__ pw)
{
    __shared__ float z_sh[80];         // raw z for t < 74
    const int b = blockIdx.x;
    const int tid = threadIdx.x;
    float* p = pw + (size_t)b * PSTRIDE;

    if (tid < OUTD) {
        const float* q = part + (size_t)b * 4 * PART_STRIDE + tid;
        float z = q[0] + q[PART_STRIDE] + q[2 * PART_STRIDE]
                + q[3 * PART_STRIDE] + fc_b[tid];
        if (tid < 74) z_sh[tid] = z;
        if (tid < 64)                      p[K_OFF + tid] = tanhf(z);
        else if (tid == 65)                p[G_OFF] = sigmoidf_(z);
        else if (tid == 73)                p[GAMMA_OFF] = softplusf_(z) + 1.f;
        else if (tid >= 74 && tid < 138)   p[E_OFF + (tid - 74)] = sigmoidf_(z);
        else if (tid >= 138)               p[A_OFF + (tid - 138)] = tanhf(z);
    }
    __syncthreads();

    if (tid < 64) {
        float kv = tanhf(z_sh[tid]);
        float ss = kv * kv;
        #pragma unroll
        for (int m = 1; m < 64; m <<= 1) ss += __shfl_xor(ss, m, 64);
        if (tid == 0) {
            float kn = fmaxf(sqrtf(ss), 1e-8f);
            float beta = softplusf_(z_sh[64]);
            p[COMBO_OFF] = beta / kn;
            float mx = -1e30f;
            #pragma unroll
            for (int q = 0; q < 7; ++q) mx = fmaxf(mx, z_sh[66 + q]);
            float ev[7], se = 0.f;
            #pragma unroll
            for (int q = 0; q < 7; ++q) {
                ev[q] = __expf(z_sh[66 + q] - mx);
                se += ev[q];
            }
            float inv = 1.f / se;
            #pragma unroll
            for (int q = 0; q < 7; ++q) p[S_OFF + q] = ev[q] * inv;
        }
    }
}

// ---------------------------------------------------------------------------
// 256-thread block reduce, fixed order -> deterministic
// ---------------------------------------------------------------------------
__device__ __forceinline__ float block_reduce_sum4(float v, float* red) {
    #pragma unroll
    for (int m = 1; m < 64; m <<= 1) v += __shfl_xor(v, m, 64);
    int wid = threadIdx.x >> 6;
    if ((threadIdx.x & 63) == 0) red[wid] = v;
    __syncthreads();
    float x = red[0] + red[1] + red[2] + red[3];
    __syncthreads();
    return x;
}

// ---------------------------------------------------------------------------
// Kernel S (R6-proven shape): 16 lanes/row (16B/lane, fully contiguous 1KB
// per wave instr), unroll 8, exp fused, per-(b,quarter) exp-sums -> esum.
// 2048 blocks x 256 threads (8 blocks/CU). Max-free softmax is exact.
// ---------------------------------------------------------------------------
__global__ __launch_bounds__(256) void score_kernel(
    const float* __restrict__ memory, const float* __restrict__ pw,
    float* __restrict__ sc, float* __restrict__ esum)
{
    __shared__ float red[4];
    const int tid = threadIdx.x;
    const int b = blockIdx.x >> 2;
    const int rbase = (blockIdx.x & 3) * 512;
    const int lane16 = tid & 15;
    const int rgrp = tid >> 4;            // 0..15
    const float* p = pw + (size_t)b * PSTRIDE;
    const float4 k4 = *(const float4*)(p + K_OFF + lane16 * 4);
    const float combo = p[COMBO_OFF];
    const float* memb = memory + (size_t)b * RR * CC;

    float lsum = 0.f;
    #pragma unroll 8
    for (int i = 0; i < 32; ++i) {
        int r = rbase + i * 16 + rgrp;
        float4 m4 = *(const float4*)(memb + (size_t)r * CC + lane16 * 4);
        float num = m4.x * k4.x + m4.y * k4.y + m4.z * k4.z + m4.w * k4.w;
        float ssq = m4.x * m4.x + m4.y * m4.y + m4.z * m4.z + m4.w * m4.w;
        #pragma unroll
        for (int m = 1; m < 16; m <<= 1) {
            num += __shfl_xor(num, m, 64);
            ssq += __shfl_xor(ssq, m, 64);
        }
        if (lane16 == 0) {
            float mn = fmaxf(sqrtf(ssq), 1e-8f);
            float ev = __expf(combo * num / mn);
            sc[(size_t)b * RR + r] = ev;
            lsum += ev;
        }
    }
    float bs = block_reduce_sum4(lsum, red);
    if (tid == 0) esum[blockIdx.x] = bs;
}

// ---------------------------------------------------------------------------
// 16-wave (1024-thread) block reduce, fixed order -> deterministic
// ---------------------------------------------------------------------------
__device__ __forceinline__ float block_reduce_sum16(float v, float* red) {
    #pragma unroll
    for (int m = 1; m < 64; m <<= 1) v += __shfl_xor(v, m, 64);
    int wid = threadIdx.x >> 6;
    if ((threadIdx.x & 63) == 0) red[wid] = v;
    __syncthreads();
    if (threadIdx.x < 16) {
        float x = red[threadIdx.x];
        #pragma unroll
        for (int m = 1; m < 16; m <<= 1) x += __shfl_xor(x, m, 64);
        if (threadIdx.x == 0) red[0] = x;
    }
    __syncthreads();
    float r = red[0];
    __syncthreads();
    return r;
}

// ---------------------------------------------------------------------------
// Kernel WU (R10-proven): per-batch weight pipeline + memory update.
// 512 blocks x 1024 threads; plain loads/stores; w stays in LDS; phase B
// 4-row batched loads, 8 lanes/row.
// ---------------------------------------------------------------------------
__global__ __launch_bounds__(1024) void wu_kernel(
    const float* __restrict__ memory, const float* __restrict__ sc,
    const float* __restrict__ esum, const float* __restrict__ prev_w,
    const float* __restrict__ pw, float* __restrict__ out_w,
    float* __restrict__ out_mem)
{
    __shared__ float wg[RR];       // gated weights -> final w
    __shared__ float wps[RR];      // w_p
    __shared__ float red[16];

    const int b = blockIdx.x;
    const int tid = threadIdx.x;
    const float* p = pw + (size_t)b * PSTRIDE;
    const float g = p[G_OFF];
    const float gamma = p[GAMMA_OFF];
    const float s0 = p[S_OFF + 0], s1 = p[S_OFF + 1], s2 = p[S_OFF + 2],
                s3 = p[S_OFF + 3], s4 = p[S_OFF + 4], s5 = p[S_OFF + 5],
                s6 = p[S_OFF + 6];
    const float* eb = esum + (size_t)b * 4;
    const float se = eb[0] + eb[1] + eb[2] + eb[3];
    const float gi = g / se, omg = 1.f - g;

    // gate: 2 rows/thread
    {
        const int r2 = tid * 2;
        float2 ev = *(const float2*)(sc + (size_t)b * RR + r2);
        float2 pv = *(const float2*)(prev_w + (size_t)b * RR + r2);
        wg[r2]     = gi * ev.x + omg * pv.x;
        wg[r2 + 1] = gi * ev.y + omg * pv.y;
    }
    __syncthreads();

    // 7-tap circular conv + pow
    float lp = 0.f;
    {
        const int r2 = tid * 2;
        #pragma unroll
        for (int q = 0; q < 2; ++q) {
            int r = r2 + q;
            float acc = s0 * wg[(r - 3) & (RR - 1)]
                      + s1 * wg[(r - 2) & (RR - 1)]
                      + s2 * wg[(r - 1) & (RR - 1)]
                      + s3 * wg[r]
                      + s4 * wg[(r + 1) & (RR - 1)]
                      + s5 * wg[(r + 2) & (RR - 1)]
                      + s6 * wg[(r + 3) & (RR - 1)];
            float v = __powf(acc, gamma);
            wps[r] = v;
            lp += v;
        }
    }
    const float ps = block_reduce_sum16(lp, red);   // internal barrier: conv done
    const float invp = 1.f / (ps + 1e-16f);

    // normalize -> out_w + stash w in wg for phase B
    {
        const int r2 = tid * 2;
        float w0 = wps[r2] * invp;
        float w1 = wps[r2 + 1] * invp;
        wg[r2] = w0;
        wg[r2 + 1] = w1;
        *(float2*)(out_w + (size_t)b * RR + r2) = make_float2(w0, w1);
    }
    __syncthreads();

    // phase B: memory update. 8 lanes/row, 4-row batched loads, plain stores.
    const int lane8 = tid & 7;
    const int rgrp = tid >> 3;             // 0..127
    const f32x4 ea = *(const f32x4*)(p + E_OFF + lane8 * 8);
    const f32x4 eb2 = *(const f32x4*)(p + E_OFF + lane8 * 8 + 4);
    const f32x4 aa = *(const f32x4*)(p + A_OFF + lane8 * 8);
    const f32x4 ab = *(const f32x4*)(p + A_OFF + lane8 * 8 + 4);
    const float* memb = memory + (size_t)b * RR * CC;
    float* omb = out_mem + (size_t)b * RR * CC;

    #pragma unroll
    for (int mi = 0; mi < 4; ++mi) {
        f32x4 ma[4], mb[4];
        float wv[4];
        #pragma unroll
        for (int j = 0; j < 4; ++j) {
            int r = (mi * 4 + j) * 128 + rgrp;
            const f32x4* mp = (const f32x4*)(memb + (size_t)r * CC + lane8 * 8);
            ma[j] = mp[0];
            mb[j] = mp[1];
            wv[j] = wg[r];
        }
        #pragma unroll
        for (int j = 0; j < 4; ++j) {
            int r = (mi * 4 + j) * 128 + rgrp;
            f32x4 oa, ob;
            oa.x = ma[j].x * (1.f - wv[j] * ea.x) + wv[j] * aa.x;
            oa.y = ma[j].y * (1.f - wv[j] * ea.y) + wv[j] * aa.y;
            oa.z = ma[j].z * (1.f - wv[j] * ea.z) + wv[j] * aa.z;
            oa.w = ma[j].w * (1.f - wv[j] * ea.w) + wv[j] * aa.w;
            ob.x = mb[j].x * (1.f - wv[j] * eb2.x) + wv[j] * ab.x;
            ob.y = mb[j].y * (1.f - wv[j] * eb2.y) + wv[j] * ab.y;
            ob.z = mb[j].z * (1.f - wv[j] * eb2.z) + wv[j] * ab.z;
            ob.w = mb[j].w * (1.f - wv[j] * eb2.w) + wv[j] * ab.w;
            f32x4* op = (f32x4*)(omb + (size_t)r * CC + lane8 * 8);
            op[0] = oa;
            op[1] = ob;
        }
    }
}

extern "C" void kernel_launch(void* const* d_in, const int* in_sizes, int n_in,
                              void* d_out, int out_size, void* d_ws, size_t ws_size,
                              hipStream_t stream) {
    const float* h      = (const float*)d_in[0];
    const float* prev_w = (const float*)d_in[1];
    const float* memory = (const float*)d_in[2];
    const float* fc_w   = (const float*)d_in[3];
    const float* fc_b   = (const float*)d_in[4];

    float* pw      = (float*)d_ws;              // 512*208 floats
    float* out_w   = (float*)d_out;             // B*R
    float* out_mem = out_w + (size_t)BB * RR;   // B*R*C

    const size_t pw_f   = (size_t)BB * PSTRIDE;
    const size_t br_f   = (size_t)BB * RR;
    const size_t es_f   = (size_t)BB * 4;
    const size_t part_f = (size_t)BB * 4 * PART_STRIDE;
    const size_t need_f = pw_f + br_f + es_f + part_f;

    float* sc   = pw + pw_f;
    float* esum = sc + br_f;
    float* part = esum + es_f;

    if (ws_size >= need_f * sizeof(float)) {
        params_part_kernel<<<256, 256, 0, stream>>>(h, fc_w, part);
        params_combine_kernel<<<BB, 256, 0, stream>>>(part, fc_b, pw);
        score_kernel<<<BB * 4, 256, 0, stream>>>(memory, pw, sc, esum);
        wu_kernel<<<BB, 1024, 0, stream>>>(memory, sc, esum, prev_w, pw,
                                           out_w, out_mem);
    } else {
        // fallback (should not trigger; ws ~800 MB, need ~6.5 MB):
        // sc into out_mem head, esum into pw tail region.
        float* sc_fb   = out_mem;
        float* esum_fb = pw + pw_f;
        float* part_fb = esum_fb + es_f;
        params_part_kernel<<<256, 256, 0, stream>>>(h, fc_w, part_fb);
        params_combine_kernel<<<BB, 256, 0, stream>>>(part_fb, fc_b, pw);
        score_kernel<<<BB * 4, 256, 0, stream>>>(memory, pw, sc_fb, esum_fb);
        wu_kernel<<<BB, 1024, 0, stream>>>(memory, sc_fb, esum_fb, prev_w, pw,
                                           out_w, out_mem);
    }
}

// Round 12
// 188.970 us; speedup vs baseline: 1.1799x; 1.0128x over previous
//
#include <hip/hip_runtime.h>
#include <math.h>

// Problem constants (from reference setup_inputs)
#define BB 512
#define HH 512
#define RR 2048
#define CC 64
#define OUTD 202          // 3*64 + 2*3 + 4
// params workspace layout per batch (floats)
#define PSTRIDE 208
#define K_OFF 0
#define E_OFF 64
#define A_OFF 128
#define S_OFF 192         // 7 softmaxed shift weights
#define COMBO_OFF 199     // beta / k_n
#define G_OFF 200
#define GAMMA_OFF 201

#define PART_STRIDE 224   // padded 202, per (batch, hq) partial row

typedef float f32x4 __attribute__((ext_vector_type(4)));

__device__ __forceinline__ float softplusf_(float x) {
    return (x > 20.f) ? x : log1pf(expf(x));
}
__device__ __forceinline__ float sigmoidf_(float x) {
    return 1.f / (1.f + expf(-x));
}

// ---------------------------------------------------------------------------
// Kernel A1: split-K partial GEMM (proven R11). 256 blocks = 64 bg x 4 hq.
// ---------------------------------------------------------------------------
__global__ __launch_bounds__(256) void params_part_kernel(
    const float* __restrict__ h, const float* __restrict__ fc_w,
    float* __restrict__ part)
{
    __shared__ float h_sh[8][128];
    const int tid = threadIdx.x;
    const int bg = blockIdx.x >> 2;
    const int hq = blockIdx.x & 3;
    const int b0 = bg * 8;
    const int h0 = hq * 128;

    for (int idx = tid; idx < 8 * 128; idx += 256) {
        int j = idx >> 7, i = idx & 127;
        h_sh[j][i] = h[(size_t)(b0 + j) * HH + h0 + i];
    }
    __syncthreads();

    if (tid < OUTD) {
        float acc[8];
        #pragma unroll
        for (int j = 0; j < 8; ++j) acc[j] = 0.f;
        const float4* wr = (const float4*)(fc_w + (size_t)tid * HH + h0);
        #pragma unroll 4
        for (int i4 = 0; i4 < 32; ++i4) {
            float4 wv = wr[i4];
            int i = i4 * 4;
            #pragma unroll
            for (int j = 0; j < 8; ++j) {
                acc[j] = fmaf(wv.x, h_sh[j][i + 0], acc[j]);
                acc[j] = fmaf(wv.y, h_sh[j][i + 1], acc[j]);
                acc[j] = fmaf(wv.z, h_sh[j][i + 2], acc[j]);
                acc[j] = fmaf(wv.w, h_sh[j][i + 3], acc[j]);
            }
        }
        #pragma unroll
        for (int j = 0; j < 8; ++j) {
            part[((size_t)(b0 + j) * 4 + hq) * PART_STRIDE + tid] = acc[j];
        }
    }
}

// ---------------------------------------------------------------------------
// Kernel A2: combine partials + bias -> activations -> packed params (R11).
// ---------------------------------------------------------------------------
__global__ __launch_bounds__(256) void params_combine_kernel(
    const float* __restrict__ part, const float* __restrict__ fc_b,
    float* __restrict__ pw)
{
    __shared__ float z_sh[80];
    const int b = blockIdx.x;
    const int tid = threadIdx.x;
    float* p = pw + (size_t)b * PSTRIDE;

    if (tid < OUTD) {
        const float* q = part + (size_t)b * 4 * PART_STRIDE + tid;
        float z = q[0] + q[PART_STRIDE] + q[2 * PART_STRIDE]
                + q[3 * PART_STRIDE] + fc_b[tid];
        if (tid < 74) z_sh[tid] = z;
        if (tid < 64)                      p[K_OFF + tid] = tanhf(z);
        else if (tid == 65)                p[G_OFF] = sigmoidf_(z);
        else if (tid == 73)                p[GAMMA_OFF] = softplusf_(z) + 1.f;
        else if (tid >= 74 && tid < 138)   p[E_OFF + (tid - 74)] = sigmoidf_(z);
        else if (tid >= 138)               p[A_OFF + (tid - 138)] = tanhf(z);
    }
    __syncthreads();

    if (tid < 64) {
        float kv = tanhf(z_sh[tid]);
        float ss = kv * kv;
        #pragma unroll
        for (int m = 1; m < 64; m <<= 1) ss += __shfl_xor(ss, m, 64);
        if (tid == 0) {
            float kn = fmaxf(sqrtf(ss), 1e-8f);
            float beta = softplusf_(z_sh[64]);
            p[COMBO_OFF] = beta / kn;
            float mx = -1e30f;
            #pragma unroll
            for (int q = 0; q < 7; ++q) mx = fmaxf(mx, z_sh[66 + q]);
            float ev[7], se = 0.f;
            #pragma unroll
            for (int q = 0; q < 7; ++q) {
                ev[q] = __expf(z_sh[66 + q] - mx);
                se += ev[q];
            }
            float inv = 1.f / se;
            #pragma unroll
            for (int q = 0; q < 7; ++q) p[S_OFF + q] = ev[q] * inv;
        }
    }
}

// ---------------------------------------------------------------------------
// 256-thread block reduce, fixed order -> deterministic
// ---------------------------------------------------------------------------
__device__ __forceinline__ float block_reduce_sum4(float v, float* red) {
    #pragma unroll
    for (int m = 1; m < 64; m <<= 1) v += __shfl_xor(v, m, 64);
    int wid = threadIdx.x >> 6;
    if ((threadIdx.x & 63) == 0) red[wid] = v;
    __syncthreads();
    float x = red[0] + red[1] + red[2] + red[3];
    __syncthreads();
    return x;
}

// ---------------------------------------------------------------------------
// Kernel S (R11): pure read streamer, 2048 x 256, 16 lanes/row, exp fused,
// per-(b,quarter) exp-sums -> esum. Max-free softmax is exact (|arg|<=beta).
// ---------------------------------------------------------------------------
__global__ __launch_bounds__(256) void score_kernel(
    const float* __restrict__ memory, const float* __restrict__ pw,
    float* __restrict__ sc, float* __restrict__ esum)
{
    __shared__ float red[4];
    const int tid = threadIdx.x;
    const int b = blockIdx.x >> 2;
    const int rbase = (blockIdx.x & 3) * 512;
    const int lane16 = tid & 15;
    const int rgrp = tid >> 4;            // 0..15
    const float* p = pw + (size_t)b * PSTRIDE;
    const float4 k4 = *(const float4*)(p + K_OFF + lane16 * 4);
    const float combo = p[COMBO_OFF];
    const float* memb = memory + (size_t)b * RR * CC;

    float lsum = 0.f;
    #pragma unroll 8
    for (int i = 0; i < 32; ++i) {
        int r = rbase + i * 16 + rgrp;
        float4 m4 = *(const float4*)(memb + (size_t)r * CC + lane16 * 4);
        float num = m4.x * k4.x + m4.y * k4.y + m4.z * k4.z + m4.w * k4.w;
        float ssq = m4.x * m4.x + m4.y * m4.y + m4.z * m4.z + m4.w * m4.w;
        #pragma unroll
        for (int m = 1; m < 16; m <<= 1) {
            num += __shfl_xor(num, m, 64);
            ssq += __shfl_xor(ssq, m, 64);
        }
        if (lane16 == 0) {
            float mn = fmaxf(sqrtf(ssq), 1e-8f);
            float ev = __expf(combo * num / mn);
            sc[(size_t)b * RR + r] = ev;
            lsum += ev;
        }
    }
    float bs = block_reduce_sum4(lsum, red);
    if (tid == 0) esum[blockIdx.x] = bs;
}

// ---------------------------------------------------------------------------
// Kernel W: per-batch weight pipeline (R2-proven shape, 512 x 256).
// sc/prev_w reads are cache-warm (just written / 4MB). Writes final w ONLY
// to out_w (update re-reads it; no extra ws round trip).
// ---------------------------------------------------------------------------
__global__ __launch_bounds__(256) void weight_kernel(
    const float* __restrict__ sc, const float* __restrict__ esum,
    const float* __restrict__ prev_w, const float* __restrict__ pw,
    float* __restrict__ out_w)
{
    __shared__ float buf[RR];
    __shared__ float wg[RR];
    __shared__ float red[4];
    const int b = blockIdx.x;
    const int tid = threadIdx.x;
    const float* p = pw + (size_t)b * PSTRIDE;
    const float g = p[G_OFF];
    const float gamma = p[GAMMA_OFF];
    const float s0 = p[S_OFF + 0], s1 = p[S_OFF + 1], s2 = p[S_OFF + 2],
                s3 = p[S_OFF + 3], s4 = p[S_OFF + 4], s5 = p[S_OFF + 5],
                s6 = p[S_OFF + 6];
    const float* eb = esum + (size_t)b * 4;
    const float se = eb[0] + eb[1] + eb[2] + eb[3];
    const float gi = g / se, omg = 1.f - g;

    // gate: 8 rows/thread, float2 vector loads
    #pragma unroll
    for (int t = 0; t < 4; ++t) {
        int r2 = (t * 256 + tid) * 2;
        float2 ev = *(const float2*)(sc + (size_t)b * RR + r2);
        float2 pv = *(const float2*)(prev_w + (size_t)b * RR + r2);
        wg[r2]     = gi * ev.x + omg * pv.x;
        wg[r2 + 1] = gi * ev.y + omg * pv.y;
    }
    __syncthreads();

    // 7-tap circular conv + pow
    float lp = 0.f;
    #pragma unroll
    for (int t = 0; t < 8; ++t) {
        int r = t * 256 + tid;
        float acc = s0 * wg[(r - 3) & (RR - 1)]
                  + s1 * wg[(r - 2) & (RR - 1)]
                  + s2 * wg[(r - 1) & (RR - 1)]
                  + s3 * wg[r]
                  + s4 * wg[(r + 1) & (RR - 1)]
                  + s5 * wg[(r + 2) & (RR - 1)]
                  + s6 * wg[(r + 3) & (RR - 1)];
        float v = __powf(acc, gamma);
        buf[r] = v;
        lp += v;
    }
    const float ps = block_reduce_sum4(lp, red);   // barrier: conv reads done
    const float invp = 1.f / (ps + 1e-16f);

    #pragma unroll
    for (int t = 0; t < 4; ++t) {
        int r2 = (t * 256 + tid) * 2;
        *(float2*)(out_w + (size_t)b * RR + r2) =
            make_float2(buf[r2] * invp, buf[r2 + 1] * invp);
    }
}

// ---------------------------------------------------------------------------
// Kernel U: pure read+write streamer (2048 x 256, no barriers). Reads w from
// out_w (4MB, L2/L3-warm), memory (reverse order: L3-MRU end first — score
// just refilled L3 with exactly this 256MB array). 4-row batched loads,
// PLAIN stores (NT = +50% WRITE_SIZE, proven R7 vs R8).
// ---------------------------------------------------------------------------
__global__ __launch_bounds__(256) void update_kernel(
    const float* __restrict__ memory, const float* __restrict__ w,
    const float* __restrict__ pw, float* __restrict__ out_mem)
{
    const int bid = (int)gridDim.x - 1 - (int)blockIdx.x;
    const int b = bid >> 2;
    const int rbase = (bid & 3) * 512;
    const int tid = threadIdx.x;
    const int lane8 = tid & 7;
    const int rgrp = tid >> 3;            // 0..31
    const float* p = pw + (size_t)b * PSTRIDE;
    const f32x4 ea = *(const f32x4*)(p + E_OFF + lane8 * 8);
    const f32x4 eb2 = *(const f32x4*)(p + E_OFF + lane8 * 8 + 4);
    const f32x4 aa = *(const f32x4*)(p + A_OFF + lane8 * 8);
    const f32x4 ab = *(const f32x4*)(p + A_OFF + lane8 * 8 + 4);
    const float* memb = memory + (size_t)b * RR * CC;
    float* omb = out_mem + (size_t)b * RR * CC;
    const float* wb = w + (size_t)b * RR;

    #pragma unroll
    for (int mi = 0; mi < 4; ++mi) {
        f32x4 ma[4], mb[4];
        float wv[4];
        #pragma unroll
        for (int j = 0; j < 4; ++j) {
            int r = rbase + (mi * 4 + j) * 32 + rgrp;
            const f32x4* mp = (const f32x4*)(memb + (size_t)r * CC + lane8 * 8);
            ma[j] = mp[0];
            mb[j] = mp[1];
            wv[j] = wb[r];
        }
        #pragma unroll
        for (int j = 0; j < 4; ++j) {
            int r = rbase + (mi * 4 + j) * 32 + rgrp;
            f32x4 oa, ob;
            oa.x = ma[j].x * (1.f - wv[j] * ea.x) + wv[j] * aa.x;
            oa.y = ma[j].y * (1.f - wv[j] * ea.y) + wv[j] * aa.y;
            oa.z = ma[j].z * (1.f - wv[j] * ea.z) + wv[j] * aa.z;
            oa.w = ma[j].w * (1.f - wv[j] * ea.w) + wv[j] * aa.w;
            ob.x = mb[j].x * (1.f - wv[j] * eb2.x) + wv[j] * ab.x;
            ob.y = mb[j].y * (1.f - wv[j] * eb2.y) + wv[j] * ab.y;
            ob.z = mb[j].z * (1.f - wv[j] * eb2.z) + wv[j] * ab.z;
            ob.w = mb[j].w * (1.f - wv[j] * eb2.w) + wv[j] * ab.w;
            f32x4* op = (f32x4*)(omb + (size_t)r * CC + lane8 * 8);
            op[0] = oa;
            op[1] = ob;
        }
    }
}

extern "C" void kernel_launch(void* const* d_in, const int* in_sizes, int n_in,
                              void* d_out, int out_size, void* d_ws, size_t ws_size,
                              hipStream_t stream) {
    const float* h      = (const float*)d_in[0];
    const float* prev_w = (const float*)d_in[1];
    const float* memory = (const float*)d_in[2];
    const float* fc_w   = (const float*)d_in[3];
    const float* fc_b   = (const float*)d_in[4];

    float* pw      = (float*)d_ws;              // 512*208 floats
    float* out_w   = (float*)d_out;             // B*R
    float* out_mem = out_w + (size_t)BB * RR;   // B*R*C

    const size_t pw_f   = (size_t)BB * PSTRIDE;
    const size_t br_f   = (size_t)BB * RR;
    const size_t es_f   = (size_t)BB * 4;
    const size_t part_f = (size_t)BB * 4 * PART_STRIDE;
    const size_t need_f = pw_f + br_f + es_f + part_f;

    float* sc   = pw + pw_f;
    float* esum = sc + br_f;
    float* part = esum + es_f;

    if (ws_size >= need_f * sizeof(float)) {
        params_part_kernel<<<256, 256, 0, stream>>>(h, fc_w, part);
        params_combine_kernel<<<BB, 256, 0, stream>>>(part, fc_b, pw);
        score_kernel<<<BB * 4, 256, 0, stream>>>(memory, pw, sc, esum);
        weight_kernel<<<BB, 256, 0, stream>>>(sc, esum, prev_w, pw, out_w);
        update_kernel<<<BB * 4, 256, 0, stream>>>(memory, out_w, pw, out_mem);
    } else {
        // fallback (ws ~800 MB in practice; keep a safe path anyway):
        // sc aliased onto out_mem head — read fully before update overwrites,
        // ordered by kernel boundaries.
        float* sc_fb   = out_mem;
        float* esum_fb = pw + pw_f;
        float* part_fb = esum_fb + es_f;
        params_part_kernel<<<256, 256, 0, stream>>>(h, fc_w, part_fb);
        params_combine_kernel<<<BB, 256, 0, stream>>>(part_fb, fc_b, pw);
        score_kernel<<<BB * 4, 256, 0, stream>>>(memory, pw, sc_fb, esum_fb);
        weight_kernel<<<BB, 256, 0, stream>>>(sc_fb, esum_fb, prev_w, pw, out_w);
        update_kernel<<<BB * 4, 256, 0, stream>>>(memory, out_w, pw, out_mem);
    }
}